// Round 1
// baseline (931.046 us; speedup 1.0000x reference)
//
#include <hip/hip_runtime.h>
#include <float.h>

// Problem constants (B=32 queries, D=128, K=16).
#define BQ 32
#define DIM 128
#define TOPK 16
#define G1 768          // phase-1 blocks
#define T1 256          // phase-1 threads (4 waves)
#define T2 256          // phase-2 threads
#define NCAND (G1*16)   // candidates per query entering phase 2 = 12288

// ---------------- phase 0: q = query @ Wq^T + bq (stored transposed) + norms ----------
__global__ void ph0_qproj(const float* __restrict__ query, const float* __restrict__ Wq,
                          const float* __restrict__ bq,
                          float* __restrict__ qT, float* __restrict__ qn2,
                          float* __restrict__ sinvq)
{
    const int b = blockIdx.x;     // query row
    const int d = threadIdx.x;    // output dim
    float s = bq[d];
    #pragma unroll 8
    for (int kk = 0; kk < DIM; ++kk)
        s = fmaf(query[b * DIM + kk], Wq[d * DIM + kk], s);
    qT[d * BQ + b] = s;
    __shared__ float red[DIM];
    red[d] = s * s;
    __syncthreads();
    for (int off = DIM / 2; off >= 1; off >>= 1) {
        if (d < off) red[d] += red[d + off];
        __syncthreads();
    }
    if (d == 0) {
        qn2[b] = red[0];
        sinvq[b] = 1.0f / sqrtf(red[0]);
    }
}

// ---------------- phase 1: scores + per-block top-16/query + min-d2 ----------
__global__ __launch_bounds__(T1, 3) void ph1_scan(
    const float* __restrict__ mem, const float* __restrict__ imp,
    const int* __restrict__ tsp, const float* __restrict__ qT,
    const float* __restrict__ sinvq, const float* __restrict__ qn2,
    const int* __restrict__ ctp,
    float* __restrict__ cand_sc, int* __restrict__ cand_ix,
    float* __restrict__ minD_ws, int N, int C, int iters)
{
    // per-wave transpose buffer: 64 rows x (32 acc + k1,k2,m2,validflag), stride 36
    __shared__ float trbuf[4][64 * 36];   // 36,864 B

    const int tid = threadIdx.x;
    const int wave = tid >> 6;
    const int lane = tid & 63;
    const int g = blockIdx.x;
    const int n0 = g * C;
    const int n1 = (n0 + C < N) ? (n0 + C) : N;
    const int qsel = lane & 31;
    const int hsel = lane >> 5;

    const float invct = 1.0f / ((float)(*ctp) + 1.0f);
    const float sq = sinvq[qsel];
    const float qn2s = qn2[qsel];

    float top_s[TOPK];
    int   top_i[TOPK];
    #pragma unroll
    for (int j = 0; j < TOPK; ++j) { top_s[j] = -FLT_MAX; top_i[j] = 0; }
    float mind = FLT_MAX;

    float* tb = &trbuf[wave][0];

    for (int it = 0; it < iters; ++it) {
        const int rowbase = n0 + it * (4 * 64) + wave * 64;   // wave-uniform
        if (rowbase < n1) {
            const int row = rowbase + lane;
            const bool valid = row < n1;
            const int rc = valid ? row : (n1 - 1);
            const float4* mrow = (const float4*)(mem + (size_t)rc * DIM);

            float acc[BQ];
            #pragma unroll
            for (int b = 0; b < BQ; ++b) acc[b] = 0.0f;
            float m2 = 0.0f;

            float4 pf[4];
            #pragma unroll
            for (int j = 0; j < 4; ++j) pf[j] = mrow[j];

            #pragma unroll 1
            for (int dd = 0; dd < 8; ++dd) {
                #pragma unroll
                for (int jj = 0; jj < 4; ++jj) {
                    const int d4 = dd * 4 + jj;
                    float4 u = pf[jj];
                    const int nx = (d4 + 4 < 32) ? (d4 + 4) : 31;
                    pf[jj] = mrow[nx];
                    m2 = fmaf(u.x, u.x, fmaf(u.y, u.y, fmaf(u.z, u.z, fmaf(u.w, u.w, m2))));
                    const float* qp = qT + d4 * (4 * BQ);   // uniform address -> s_load
                    #pragma unroll
                    for (int b = 0; b < BQ; ++b) acc[b] = fmaf(u.x, qp[b], acc[b]);
                    #pragma unroll
                    for (int b = 0; b < BQ; ++b) acc[b] = fmaf(u.y, qp[BQ + b], acc[b]);
                    #pragma unroll
                    for (int b = 0; b < BQ; ++b) acc[b] = fmaf(u.z, qp[2 * BQ + b], acc[b]);
                    #pragma unroll
                    for (int b = 0; b < BQ; ++b) acc[b] = fmaf(u.w, qp[3 * BQ + b], acc[b]);
                }
            }

            // per-row score constants
            const float invm = rsqrtf(m2);
            const float recn = ((float)tsp[rc] + 1.0f) * invct;
            const float impf = fmaf(0.5f, imp[rc], 0.5f);
            const float k1 = 0.7f * invm * impf;
            const float k2 = 0.3f * recn * impf;

            // transpose through LDS (wave-private; compiler orders aliasing ds ops)
            #pragma unroll
            for (int b = 0; b < BQ; ++b) tb[lane * 36 + b] = acc[b];
            tb[lane * 36 + 32] = k1;
            tb[lane * 36 + 33] = k2;
            tb[lane * 36 + 34] = m2;
            tb[lane * 36 + 35] = valid ? 1.0f : -1.0f;

            #pragma unroll 1
            for (int j = 0; j < 32; ++j) {
                const int rr = (hsel << 5) + j;
                const float a = tb[rr * 36 + qsel];
                const float4 kk = *(const float4*)&tb[rr * 36 + 32]; // k1,k2,m2,vf
                const float score = fmaf(a, kk.x * sq, kk.y);
                const float d2 = fmaf(-2.0f, a, qn2s + kk.z);
                if (kk.w > 0.0f) {
                    mind = fminf(mind, d2);
                    if (score > top_s[TOPK - 1]) {
                        float cs = score; int ci = rowbase + rr;
                        #pragma unroll
                        for (int p = 0; p < TOPK; ++p) {
                            const bool gt = cs > top_s[p];
                            const float tv = top_s[p]; const int tx = top_i[p];
                            top_s[p] = gt ? cs : tv;  top_i[p] = gt ? ci : tx;
                            cs = gt ? tv : cs;        ci = gt ? tx : ci;
                        }
                    }
                }
            }
        }
    }

    // ---- block merge: dump lists to LDS, per-query 128 -> 16 extraction ----
    __syncthreads();
    float* dsc = &trbuf[0][0];            // 256*16 floats
    int*   dix = (int*)(dsc + T1 * TOPK); // 256*16 ints
    float* dmn = dsc + 2 * T1 * TOPK;     // 256 floats
    #pragma unroll
    for (int j = 0; j < TOPK; ++j) {
        dsc[tid * TOPK + j] = top_s[j];
        dix[tid * TOPK + j] = top_i[j];
    }
    dmn[tid] = mind;
    __syncthreads();

    for (int qq = 0; qq < 8; ++qq) {
        const int q = wave * 8 + qq;
        // 8 lists of 16 -> 128 candidates; 2 per lane
        float sc2[2]; int ix2[2];
        #pragma unroll
        for (int s = 0; s < 2; ++s) {
            const int c = lane * 2 + s;
            const int L = (c >> 4) * 32 + q;
            const int slot = c & 15;
            sc2[s] = dsc[L * TOPK + slot];
            ix2[s] = dix[L * TOPK + slot];
        }
        float lm = (sc2[0] >= sc2[1]) ? sc2[0] : sc2[1];
        int   ls = (sc2[0] >= sc2[1]) ? 0 : 1;
        for (int r = 0; r < TOPK; ++r) {
            float v = lm; int we = lane;
            #pragma unroll
            for (int off = 32; off >= 1; off >>= 1) {
                const float ov = __shfl_xor(v, off);
                const int   oe = __shfl_xor(we, off);
                if (ov > v || (ov == v && oe < we)) { v = ov; we = oe; }
            }
            if (lane == we) {
                cand_sc[(g * 32 + q) * TOPK + r] = lm;
                cand_ix[(g * 32 + q) * TOPK + r] = ix2[ls];
                sc2[ls] = -FLT_MAX;
                lm = (sc2[0] >= sc2[1]) ? sc2[0] : sc2[1];
                ls = (sc2[0] >= sc2[1]) ? 0 : 1;
            }
        }
    }

    if (tid < 32) {
        float m = FLT_MAX;
        #pragma unroll
        for (int l = 0; l < 8; ++l) m = fminf(m, dmn[l * 32 + tid]);
        minD_ws[g * 32 + tid] = m;
    }
}

// ---------------- phase 2: global top-16/query + novelty ----------
__global__ void ph2_final(const float* __restrict__ cand_sc, const int* __restrict__ cand_ix,
                          const float* __restrict__ minD_ws, float* __restrict__ out, int G)
{
    __shared__ float ssc[NCAND];          // 48 KB
    __shared__ float shv[4];
    __shared__ int   she[4];
    __shared__ float smin[T2];

    const int q = blockIdx.x;
    const int tid = threadIdx.x;
    const int wave = tid >> 6;
    const int lane = tid & 63;

    for (int e = tid; e < NCAND; e += T2)
        ssc[e] = cand_sc[(e >> 4) * (32 * TOPK) + q * TOPK + (e & 15)];
    __syncthreads();

    // local argmax over this thread's 48 slots (e = s*256 + tid)
    float lm = ssc[tid]; int le = tid;
    for (int s = 1; s < NCAND / T2; ++s) {
        const int e = s * T2 + tid;
        const float v = ssc[e];
        if (v > lm) { lm = v; le = e; }
    }

    for (int r = 0; r < TOPK; ++r) {
        float v = lm; int e = le;
        #pragma unroll
        for (int off = 32; off >= 1; off >>= 1) {
            const float ov = __shfl_xor(v, off);
            const int   oe = __shfl_xor(e, off);
            if (ov > v || (ov == v && oe < e)) { v = ov; e = oe; }
        }
        if (lane == 0) { shv[wave] = v; she[wave] = e; }
        __syncthreads();
        float bv = shv[0]; int be = she[0];
        #pragma unroll
        for (int w2 = 1; w2 < 4; ++w2) {
            const float wv = shv[w2]; const int wе2 = she[w2];
            if (wv > bv || (wv == bv && wе2 < be)) { bv = wv; be = wе2; }
        }
        if (le == be) {   // unique winner thread
            out[q * TOPK + r] = bv;
            const int gix = cand_ix[(be >> 4) * (32 * TOPK) + q * TOPK + (be & 15)];
            out[BQ * TOPK + q * TOPK + r] = (float)gix;
            ssc[le] = -FLT_MAX;
            lm = ssc[tid]; le = tid;
            for (int s = 1; s < NCAND / T2; ++s) {
                const int e2 = s * T2 + tid;
                const float v2 = ssc[e2];
                if (v2 > lm) { lm = v2; le = e2; }
            }
        }
        __syncthreads();
    }

    // novelty
    float m = FLT_MAX;
    for (int g2 = tid; g2 < G; g2 += T2) m = fminf(m, minD_ws[g2 * 32 + q]);
    smin[tid] = m;
    __syncthreads();
    for (int off = T2 / 2; off >= 1; off >>= 1) {
        if (tid < off) smin[tid] = fminf(smin[tid], smin[tid + off]);
        __syncthreads();
    }
    if (tid == 0) {
        const float md = sqrtf(fmaxf(smin[0], 0.0f));
        out[2 * BQ * TOPK + q] = fminf(1.0f, md * 0.1f);
    }
}

extern "C" void kernel_launch(void* const* d_in, const int* in_sizes, int n_in,
                              void* d_out, int out_size, void* d_ws, size_t ws_size,
                              hipStream_t stream) {
    const float* query      = (const float*)d_in[0];
    const float* memory     = (const float*)d_in[1];
    const float* importance = (const float*)d_in[2];
    const int*   timestamps = (const int*)d_in[3];
    const float* Wq         = (const float*)d_in[4];
    const float* bq         = (const float*)d_in[5];
    const int*   ctp        = (const int*)d_in[6];
    const int N = in_sizes[2];

    float* ws      = (float*)d_ws;
    float* qT      = ws;                       // 4096
    float* qn2     = ws + 4096;                // 32
    float* sinvq   = ws + 4128;                // 32
    float* cand_sc = ws + 4352;                // G1*32*16 = 393216
    int*   cand_ix = (int*)(ws + 4352 + G1 * 32 * TOPK);
    float* minD_ws = ws + 4352 + 2 * G1 * 32 * TOPK;  // G1*32

    const int C = (N + G1 - 1) / G1;           // rows per block
    const int iters = (C + (4 * 64) - 1) / (4 * 64);

    ph0_qproj<<<BQ, DIM, 0, stream>>>(query, Wq, bq, qT, qn2, sinvq);
    ph1_scan<<<G1, T1, 0, stream>>>(memory, importance, timestamps, qT, sinvq, qn2,
                                    ctp, cand_sc, cand_ix, minD_ws, N, C, iters);
    ph2_final<<<BQ, T2, 0, stream>>>(cand_sc, cand_ix, minD_ws, (float*)d_out, G1);
}